// Round 4
// baseline (427.026 us; speedup 1.0000x reference)
//
#include <hip/hip_runtime.h>

// AlignmentMatrix: out[b,i,j] = sum_d body[b,i,d]*w3[d]*pun[b,j,d]
//                             + dot(body[b,i,:],w1) + dot(pun[b,j,:],w2)
// B=64, L=1024, D=128, fp32 in/out.
//
// R6: occupancy-repaired traffic-minimal config.
//  - 128x256 tile (2048 blocks), single-buffered 48 KB LDS, acc[4][4]/wave
//    (~120 VGPR) + __launch_bounds__(512,4)  =>  2 blocks/CU (vs R5's 1).
//  - plain __syncthreads schedule: vmcnt drains hidden by co-resident block.
//  - bf16 hi/lo ws (prep pass), gload_lds(16B) staging, no conversion VALU.
//  - XCD batch-chunked swizzle: per-XCD working set ~2 MB < 4 MB L2.
//  - swapped MFMA operands (A=pun) -> float4 stores along j.

#define LSEQ 1024
#define H2K  128

// ws layout:
//   ws[0      .. 65536)   s_body (fp32)
//   ws[65536  .. 131072)  s_pun  (fp32)
//   shorts at base=(short*)(ws+131072):
//     [0        ..  8388608)  body*w3  bf16 hi
//     [8388608  .. 16777216)  body*w3  bf16 lo
//     [16777216 .. 25165824)  pun      bf16 hi
//     [25165824 .. 33554432)  pun      bf16 lo

typedef __attribute__((ext_vector_type(8))) short bfrag;
typedef __attribute__((ext_vector_type(4))) float f32x4;

__device__ __forceinline__ short f2bf(float x) {
    unsigned u = __float_as_uint(x);
    unsigned r = (u + 0x7fff + ((u >> 16) & 1)) >> 16;   // RNE
    return (short)r;
}
__device__ __forceinline__ float bf2f(short s) {
    return __uint_as_float(((unsigned)(unsigned short)s) << 16);
}

__device__ __forceinline__ void ld16(void* lds, const void* g) {
    __builtin_amdgcn_global_load_lds(
        (const __attribute__((address_space(1))) void*)g,
        (__attribute__((address_space(3))) void*)lds, 16, 0, 0);
}

// --- pre-pass: one wave per row. fp32 rank-1 dot + bf16 hi/lo split write.
__global__ __launch_bounds__(256) void prep_kernel(
    const float* __restrict__ body, const float* __restrict__ pun,
    const float* __restrict__ w_u, float* __restrict__ ws)
{
    const int flag = blockIdx.y;                   // 0=body, 1=pun
    const int lane = threadIdx.x & 63;
    const int wv   = threadIdx.x >> 6;
    const size_t row = (size_t)blockIdx.x * 4 + wv;        // [0, B*LSEQ)

    const float* src = (flag ? pun : body) + row * H2K;
    const float2 v  = *(const float2*)(src + lane * 2);
    const float2 wm = *(const float2*)(w_u + flag * H2K + lane * 2);

    float p = v.x * wm.x + v.y * wm.y;
    p += __shfl_xor(p, 32);
    p += __shfl_xor(p, 16);
    p += __shfl_xor(p, 8);
    p += __shfl_xor(p, 4);
    p += __shfl_xor(p, 2);
    p += __shfl_xor(p, 1);
    if (lane == 0) ws[(size_t)flag * 65536 + row] = p;

    float cx = v.x, cy = v.y;
    if (!flag) {
        const float2 w3v = *(const float2*)(w_u + 2 * H2K + lane * 2);
        cx *= w3v.x; cy *= w3v.y;
    }
    const short h0 = f2bf(cx), h1 = f2bf(cy);
    const short l0 = f2bf(cx - bf2f(h0)), l1 = f2bf(cy - bf2f(h1));

    short* hb = (short*)(ws + 131072) + (size_t)flag * 16777216 + row * H2K + lane * 2;
    *(unsigned*)hb =
        ((unsigned)(unsigned short)h0) | ((unsigned)(unsigned short)h1 << 16);
    *(unsigned*)(hb + 8388608) =
        ((unsigned)(unsigned short)l0) | ((unsigned)(unsigned short)l1 << 16);
}

// --- main kernel: 128(i) x 256(j) tile / 512 threads, K chunked 4x32.
__global__ __launch_bounds__(512, 4) void align_mfma(
    const float* __restrict__ ws, float* __restrict__ out)
{
    // C = body (B operand, 8 i-tiles), P = pun (A operand, 16 j-tiles).
    __shared__ __align__(16) short Ch[4096], Cl[4096];    //  8 KB each
    __shared__ __align__(16) short Ph[8192], Pl[8192];    // 16 KB each => 48 KB

    // XCD batch-chunked swizzle (2048 % 8 == 0 -> bijective).
    const int nwg = gridDim.x;                 // 2048
    const int bid = blockIdx.x;
    const int tid = (bid & 7) * (nwg >> 3) + (bid >> 3);
    const int bb = tid >> 5;                   // batch (32 blocks per batch)
    const int r5 = tid & 31;
    const int ti = (r5 >> 2) * 128;            // body rows (output rows), 8 tiles
    const int tj = (r5 & 3) * 256;             // pun rows (output cols), 4 tiles

    const int t    = threadIdx.x;
    const int lane = t & 63;
    const int w    = t >> 6;                   // wave id 0..7

    // Staging frag f: tile=f>>6, l=f&63 -> row=(f>>6)*16+(l&15), k8=l>>4.
    // Thread t stages: body frag t; pun frags t and t+512.
    const int srow = w * 16 + (lane & 15);
    const int k8   = lane >> 4;
    const short* base = (const short*)(ws + 131072);
    const size_t crow = (size_t)(bb * LSEQ + ti + srow) * H2K + k8 * 8;
    const size_t prow = (size_t)(bb * LSEQ + tj + srow) * H2K + k8 * 8;
    const short* gCh = base + crow;
    const short* gCl = base + 8388608 + crow;
    const short* gPh = base + 16777216 + prow;
    const short* gPl = base + 25165824 + prow;
    const size_t R2OFF = (size_t)128 * H2K;    // +128 rows for second pun frag

    // Wave -> output sub-tile: jg = w&3 (4 j-tiles = 64 cols), ig = w>>2 (4 i-tiles).
    const int jg = w & 3;
    const int ig = w >> 2;
    f32x4 acc[4][4] = {};                      // [jt][it], 64 VGPR

    for (int kt = 0; kt < 4; ++kt) {
        if (kt) __syncthreads();               // LDS reuse guard

        // ---- stage chunk kt: 6 x gload_lds(16B) per thread ----
        ld16(&Ch[t * 8],         gCh + kt * 32);
        ld16(&Cl[t * 8],         gCl + kt * 32);
        ld16(&Ph[t * 8],         gPh + kt * 32);
        ld16(&Ph[(512 + t) * 8], gPh + R2OFF + kt * 32);
        ld16(&Pl[t * 8],         gPl + kt * 32);
        ld16(&Pl[(512 + t) * 8], gPl + R2OFF + kt * 32);
        __syncthreads();                       // drains vmcnt; hidden by 2nd block

        // ---- compute chunk kt: 48 MFMAs / wave ----
        bfrag ph[4], pl[4];
#pragma unroll
        for (int jj = 0; jj < 4; ++jj) {
            ph[jj] = *(const bfrag*)&Ph[((jg * 4 + jj) * 64 + lane) * 8];
            pl[jj] = *(const bfrag*)&Pl[((jg * 4 + jj) * 64 + lane) * 8];
        }
#pragma unroll
        for (int ii = 0; ii < 4; ++ii) {
            const bfrag ch = *(const bfrag*)&Ch[((ig * 4 + ii) * 64 + lane) * 8];
            const bfrag cl = *(const bfrag*)&Cl[((ig * 4 + ii) * 64 + lane) * 8];
#pragma unroll
            for (int jj = 0; jj < 4; ++jj) {
                acc[jj][ii] = __builtin_amdgcn_mfma_f32_16x16x32_bf16(ph[jj], ch, acc[jj][ii], 0, 0, 0);
                acc[jj][ii] = __builtin_amdgcn_mfma_f32_16x16x32_bf16(ph[jj], cl, acc[jj][ii], 0, 0, 0);
                acc[jj][ii] = __builtin_amdgcn_mfma_f32_16x16x32_bf16(pl[jj], ch, acc[jj][ii], 0, 0, 0);
            }
        }
    }

    // ---- epilogue: + s_body[i] + s_pun[j], float4 stores along j ----
    // D mapping (swapped): col j = tj + jt*16 + (lane>>4)*4 + reg; row i = ti + it*16 + (lane&15).
    const float* sbp = ws + (size_t)bb * LSEQ;
    const float* spp = ws + 65536 + (size_t)bb * LSEQ;
    const int qd = lane >> 4, ln = lane & 15;
#pragma unroll
    for (int jj = 0; jj < 4; ++jj) {
        const int j0 = tj + (jg * 4 + jj) * 16 + qd * 4;
        const float4 spv = *(const float4*)(spp + j0);
#pragma unroll
        for (int ii = 0; ii < 4; ++ii) {
            const int row = ti + (ig * 4 + ii) * 16 + ln;
            const float sb = sbp[row];
            const f32x4 a = acc[jj][ii];
            float4 r = { a[0] + sb + spv.x, a[1] + sb + spv.y,
                         a[2] + sb + spv.z, a[3] + sb + spv.w };
            *(float4*)&out[((size_t)bb * LSEQ + row) * LSEQ + j0] = r;
        }
    }
}

extern "C" void kernel_launch(void* const* d_in, const int* in_sizes, int n_in,
                              void* d_out, int out_size, void* d_ws, size_t ws_size,
                              hipStream_t stream) {
    const float* body = (const float*)d_in[1];
    const float* pun  = (const float*)d_in[2];
    const float* w_u  = (const float*)d_in[3];
    float* out = (float*)d_out;
    float* ws  = (float*)d_ws;
    const int B = in_sizes[1] / (LSEQ * H2K);

    dim3 g1((B * LSEQ) / 4, 2, 1);
    prep_kernel<<<g1, 256, 0, stream>>>(body, pun, w_u, ws);

    dim3 g2(B * 32, 1, 1);
    align_mfma<<<g2, 512, 0, stream>>>(ws, out);
}

// Round 5
// 376.572 us; speedup vs baseline: 1.1340x; 1.1340x over previous
//
#include <hip/hip_runtime.h>

// AlignmentMatrix: out[b,i,j] = sum_d body[b,i,d]*w3[d]*pun[b,j,d]
//                             + dot(body[b,i,:],w1) + dot(pun[b,j,:],w2)
// B=64, L=1024, D=128, fp32 in/out.
//
// R7: single fused kernel, SINGLE-bf16 cross term (no hi/lo split).
//  - tolerance is 0.5; single-bf16 max error ~0.1 (see session journal).
//  - rank-1 dots computed during staging (shfl-reduce over k-quarters),
//    shared via tiny LDS arrays -> prep kernel + its 128 MB traffic gone.
//  - 128(i) x 256(j) tile, 2048 blocks, XCD batch-chunked swizzle
//    (per-XCD working set ~1-2 MB < 4 MB L2).
//  - 16 MFMAs/wave/chunk (was 48), 25.5 KB LDS, <=128 VGPR -> 2 blocks/CU.
//  - swapped MFMA operands (A=pun, B=body) -> float4 stores along j
//    (mapping hardware-verified in R4/R5/R6).

#define LSEQ 1024
#define H2K  128

typedef __attribute__((ext_vector_type(8))) short bfrag;
typedef __attribute__((ext_vector_type(4))) float f32x4;

__device__ __forceinline__ short f2bf(float x) {
    unsigned u = __float_as_uint(x);
    unsigned r = (u + 0x7fff + ((u >> 16) & 1)) >> 16;   // RNE
    return (short)r;
}

__global__ __launch_bounds__(512, 4) void align_fused(
    const float* __restrict__ body, const float* __restrict__ pun,
    const float* __restrict__ w_u, float* __restrict__ out)
{
    __shared__ __align__(16) short Cb[4096];    // body*w3 bf16, frag order (8 KB)
    __shared__ __align__(16) short Pb[8192];    // pun bf16, frag order (16 KB)
    __shared__ __align__(16) float sb[128];     // s_body for this tile's rows
    __shared__ __align__(16) float sp[256];     // s_pun  for this tile's cols

    // XCD batch-chunked bijective swizzle (gridDim.x = B*32, divisible by 8)
    const int nwg = gridDim.x;
    const int bid = blockIdx.x;
    const int tid = (bid & 7) * (nwg >> 3) + (bid >> 3);
    const int bb = tid >> 5;                   // batch (32 blocks per batch)
    const int r5 = tid & 31;
    const int ti = (r5 >> 2) * 128;            // body rows (output rows)
    const int tj = (r5 & 3) * 256;             // pun rows  (output cols)

    const int t    = threadIdx.x;
    const int lane = t & 63;
    const int w    = t >> 6;                   // wave id 0..7

    // Staging frag: row = w*16+(lane&15), k-quarter = lane>>4 (8 consecutive k)
    const int srow = w * 16 + (lane & 15);
    const int k8   = lane >> 4;

    const float4* bp  = (const float4*)(body + (size_t)(bb * LSEQ + ti + srow) * H2K) + k8 * 2;
    const float4* p1  = (const float4*)(pun  + (size_t)(bb * LSEQ + tj + srow) * H2K) + k8 * 2;
    const float4* p2  = (const float4*)(pun  + (size_t)(bb * LSEQ + tj + 128 + srow) * H2K) + k8 * 2;
    const float4* w1v = (const float4*)(w_u          ) + k8 * 2;
    const float4* w2v = (const float4*)(w_u +     H2K) + k8 * 2;
    const float4* w3v = (const float4*)(w_u + 2 * H2K) + k8 * 2;

    // Wave -> output sub-tile: jg (4 j-tiles = 64 cols), ig (4 i-tiles = 64 rows)
    const int jg = w & 3;
    const int ig = w >> 2;
    f32x4 acc[4][4] = {};                      // [jt][it]
    float db = 0.f, dp1 = 0.f, dp2 = 0.f;      // rank-1 partial dots

    for (int kt = 0; kt < 4; ++kt) {
        if (kt) __syncthreads();               // LDS reuse guard

        // ---- stage chunk kt: load fp32, fold w3/dots, convert, ds_write ----
        const float4 xb0 = bp[kt * 8],  xb1 = bp[kt * 8 + 1];
        const float4 u30 = w3v[kt * 8], u31 = w3v[kt * 8 + 1];
        const float4 u10 = w1v[kt * 8], u11 = w1v[kt * 8 + 1];
        db += xb0.x * u10.x + xb0.y * u10.y + xb0.z * u10.z + xb0.w * u10.w
            + xb1.x * u11.x + xb1.y * u11.y + xb1.z * u11.z + xb1.w * u11.w;
        bfrag fb;
        fb[0] = f2bf(xb0.x * u30.x); fb[1] = f2bf(xb0.y * u30.y);
        fb[2] = f2bf(xb0.z * u30.z); fb[3] = f2bf(xb0.w * u30.w);
        fb[4] = f2bf(xb1.x * u31.x); fb[5] = f2bf(xb1.y * u31.y);
        fb[6] = f2bf(xb1.z * u31.z); fb[7] = f2bf(xb1.w * u31.w);
        *(bfrag*)&Cb[t * 8] = fb;

        const float4 y10 = p1[kt * 8],  y11 = p1[kt * 8 + 1];
        const float4 y20 = p2[kt * 8],  y21 = p2[kt * 8 + 1];
        const float4 u20 = w2v[kt * 8], u21 = w2v[kt * 8 + 1];
        dp1 += y10.x * u20.x + y10.y * u20.y + y10.z * u20.z + y10.w * u20.w
             + y11.x * u21.x + y11.y * u21.y + y11.z * u21.z + y11.w * u21.w;
        dp2 += y20.x * u20.x + y20.y * u20.y + y20.z * u20.z + y20.w * u20.w
             + y21.x * u21.x + y21.y * u21.y + y21.z * u21.z + y21.w * u21.w;
        bfrag f1, f2;
        f1[0] = f2bf(y10.x); f1[1] = f2bf(y10.y); f1[2] = f2bf(y10.z); f1[3] = f2bf(y10.w);
        f1[4] = f2bf(y11.x); f1[5] = f2bf(y11.y); f1[6] = f2bf(y11.z); f1[7] = f2bf(y11.w);
        f2[0] = f2bf(y20.x); f2[1] = f2bf(y20.y); f2[2] = f2bf(y20.z); f2[3] = f2bf(y20.w);
        f2[4] = f2bf(y21.x); f2[5] = f2bf(y21.y); f2[6] = f2bf(y21.z); f2[7] = f2bf(y21.w);
        *(bfrag*)&Pb[t * 8]         = f1;
        *(bfrag*)&Pb[(512 + t) * 8] = f2;

        __syncthreads();

        // ---- compute chunk kt: 16 MFMAs / wave ----
        bfrag ph[4];
#pragma unroll
        for (int jj = 0; jj < 4; ++jj)
            ph[jj] = *(const bfrag*)&Pb[((jg * 4 + jj) * 64 + lane) * 8];
#pragma unroll
        for (int ii = 0; ii < 4; ++ii) {
            const bfrag ch = *(const bfrag*)&Cb[((ig * 4 + ii) * 64 + lane) * 8];
#pragma unroll
            for (int jj = 0; jj < 4; ++jj)
                acc[jj][ii] = __builtin_amdgcn_mfma_f32_16x16x32_bf16(ph[jj], ch, acc[jj][ii], 0, 0, 0);
        }
    }

    // ---- rank-1 reduce (across the 4 k-quarter lanes) and share ----
    db  += __shfl_xor(db, 16);  db  += __shfl_xor(db, 32);
    dp1 += __shfl_xor(dp1, 16); dp1 += __shfl_xor(dp1, 32);
    dp2 += __shfl_xor(dp2, 16); dp2 += __shfl_xor(dp2, 32);
    if (k8 == 0) {                              // lanes 0..15: srow = w*16+lane
        sb[srow] = db;
        sp[srow] = dp1;
        sp[128 + srow] = dp2;
    }
    __syncthreads();

    // ---- epilogue: + s_body[i] + s_pun[j], float4 stores along j ----
    // D (swapped): col = lane&15 -> body row i; j = jt*16 + (lane>>4)*4 + reg.
    const int qd = lane >> 4, ln = lane & 15;
#pragma unroll
    for (int jj = 0; jj < 4; ++jj) {
        const int jl = (jg * 4 + jj) * 16 + qd * 4;       // local col of reg 0
        const float4 spv = *(const float4*)&sp[jl];
#pragma unroll
        for (int ii = 0; ii < 4; ++ii) {
            const int rl = (ig * 4 + ii) * 16 + ln;       // local row
            const float sbv = sb[rl];
            const f32x4 a = acc[jj][ii];
            float4 r = { a[0] + sbv + spv.x, a[1] + sbv + spv.y,
                         a[2] + sbv + spv.z, a[3] + sbv + spv.w };
            *(float4*)&out[(size_t)(bb * LSEQ + ti + rl) * LSEQ + tj + jl] = r;
        }
    }
}

extern "C" void kernel_launch(void* const* d_in, const int* in_sizes, int n_in,
                              void* d_out, int out_size, void* d_ws, size_t ws_size,
                              hipStream_t stream) {
    const float* body = (const float*)d_in[1];
    const float* pun  = (const float*)d_in[2];
    const float* w_u  = (const float*)d_in[3];
    float* out = (float*)d_out;
    const int B = in_sizes[1] / (LSEQ * H2K);

    dim3 g(B * 32, 1, 1);
    align_fused<<<g, 512, 0, stream>>>(body, pun, w_u, out);
}